// Round 1
// baseline (670.942 us; speedup 1.0000x reference)
//
#include <hip/hip_runtime.h>
#include <hip/hip_bf16.h>
#include <math.h>

typedef unsigned long long u64;

#define NN 4096
#define NF 1024
#define NH 512
#define NC 32

// ---------------- alphas softmax (3 rows of 5) ----------------
__global__ void k_alpha(const float* __restrict__ alphas, float* __restrict__ a_sm) {
    if (blockIdx.x == 0 && threadIdx.x == 0) {
        for (int i = 0; i < 3; ++i) {
            float m = -1e30f;
            for (int j = 0; j < 5; ++j) m = fmaxf(m, alphas[i*5+j]);
            float e[5]; float s = 0.f;
            for (int j = 0; j < 5; ++j) { e[j] = expf(alphas[i*5+j] - m); s += e[j]; }
            for (int j = 0; j < 5; ++j) a_sm[i*5+j] = e[j] / s;
        }
    }
}

// ---------------- build B1 bitset + per-row nnz count ----------------
// one wave (64 threads) per row; coalesced reads via ballot
__global__ void k_bits_count(const float* __restrict__ adj, u64* __restrict__ B1,
                             int* __restrict__ rowcnt) {
    int i = blockIdx.x;
    int lane = threadIdx.x;
    const float* row = adj + (size_t)i * NN;
    u64 myword = 0;
    int cnt = 0;
    for (int j = 0; j < 64; ++j) {
        float v = row[j*64 + lane];
        u64 m = __ballot(v > 0.0f);
        if (j == lane) myword = m;
        if (lane == 0) cnt += __popcll(m);
    }
    B1[(size_t)i*64 + lane] = myword;
    if (lane == 0) rowcnt[i] = cnt;
}

// ---------------- exclusive scan of 4096 counts (1 block) ----------------
__global__ void k_scan(const int* __restrict__ rowcnt, int* __restrict__ rowptr) {
    __shared__ int sums[1024];
    int t = threadIdx.x;
    int base = t * 4;
    int a0 = rowcnt[base], a1 = rowcnt[base+1], a2 = rowcnt[base+2], a3 = rowcnt[base+3];
    sums[t] = a0 + a1 + a2 + a3;
    __syncthreads();
    for (int offs = 1; offs < 1024; offs <<= 1) {
        int v = (t >= offs) ? sums[t - offs] : 0;
        __syncthreads();
        sums[t] += v;
        __syncthreads();
    }
    int excl = (t == 0) ? 0 : sums[t-1];
    rowptr[base]   = excl;
    rowptr[base+1] = excl + a0;
    rowptr[base+2] = excl + a0 + a1;
    rowptr[base+3] = excl + a0 + a1 + a2;
    if (t == 1023) rowptr[4096] = sums[1023];
}

// ---------------- CSR fill (ballot-ordered, deterministic, column-sorted) ----------------
__global__ void k_fill(const float* __restrict__ adj, const int* __restrict__ rowptr,
                       int* __restrict__ colidx, float* __restrict__ vals) {
    int i = blockIdx.x;
    int lane = threadIdx.x;
    const float* row = adj + (size_t)i * NN;
    int pos = rowptr[i];
    for (int j = 0; j < 64; ++j) {
        float v = row[j*64 + lane];
        u64 m = __ballot(v > 0.0f);
        if (v > 0.0f) {
            int off = __popcll(m & ((1ULL << lane) - 1ULL));
            colidx[pos + off] = j*64 + lane;
            vals[pos + off] = v;
        }
        pos += __popcll(m);
    }
}

// ---------------- per-class label bitsets from one-hot y ----------------
__global__ void k_labelbits(const float* __restrict__ y, u64* __restrict__ L) {
    int j = blockIdx.x * blockDim.x + threadIdx.x;
    if (j >= NN) return;
    for (int c = 0; c < NC; ++c) {
        if (y[(size_t)j*NC + c] > 0.5f)
            atomicOr(&L[c*64 + (j >> 6)], 1ULL << (j & 63));
    }
}

// ---------------- boolean matrix product: Bout[i] = OR_{k in bits(Bidx[i])} Bdat[k] ----------------
__global__ void k_bsquare(const u64* __restrict__ Bidx, const u64* __restrict__ Bdat,
                          u64* __restrict__ Bout) {
    int i = blockIdx.x;
    int t = threadIdx.x; // 64
    __shared__ u64 ridx[64];
    ridx[t] = Bidx[(size_t)i*64 + t];
    __syncthreads();
    u64 acc = 0;
    for (int u = 0; u < 64; ++u) {
        u64 w = ridx[u];
        while (w) {
            int k = u*64 + (__ffsll((unsigned long long)w) - 1);
            acc |= Bdat[(size_t)k*64 + t];
            w &= (w - 1);
        }
    }
    Bout[(size_t)i*64 + t] = acc;
}

// ---------------- 64x64-tile bit transpose ----------------
__global__ void k_btrans(const u64* __restrict__ B, u64* __restrict__ BT) {
    int I = blockIdx.x, J = blockIdx.y;
    int t = threadIdx.x; // 64
    __shared__ u64 ld[64];
    ld[t] = B[(size_t)(I*64 + t)*64 + J];
    __syncthreads();
    u64 out = 0;
    for (int r = 0; r < 64; ++r) out |= ((ld[r] >> t) & 1ULL) << r;
    BT[(size_t)(J*64 + t)*64 + I] = out;
}

// ---------------- y_out / y_in via popcount ----------------
__global__ void k_ydist(const u64* __restrict__ B, const u64* __restrict__ L,
                        float* __restrict__ Y) {
    int i = blockIdx.x;
    int t = threadIdx.x; // 64
    __shared__ u64 row[64];
    row[t] = B[(size_t)i*64 + t];
    __syncthreads();
    if (t < NC) {
        int cnt = 0;
        for (int w = 0; w < 64; ++w) cnt += __popcll(row[w] & L[t*64 + w]);
        Y[(size_t)i*NC + t] = (float)cnt;
    }
}

// ---------------- SpMM: Y = adj @ X, X/Y are [NN, d] ----------------
__global__ void k_spmm(const int* __restrict__ rowptr, const int* __restrict__ colidx,
                       const float* __restrict__ vals, const float* __restrict__ X,
                       float* __restrict__ Y, int d) {
    int i = blockIdx.y;
    int c = blockIdx.x * 256 + threadIdx.x;
    int s = rowptr[i], e = rowptr[i+1];
    float acc = 0.f;
    for (int p = s; p < e; ++p) acc += vals[p] * X[(size_t)colidx[p]*d + c];
    Y[(size_t)i*d + c] = acc;
}

// ---------------- fused layer GEMM: C = [a0*hop | a1*yo | a2*yi | a3*(yo+yi)] @ W + b ----------------
// block tile 64x64, BK=16, 256 threads, 4x4 per thread
__global__ __launch_bounds__(256) void k_gemm(const float* __restrict__ hop,
                                              const float* __restrict__ yo,
                                              const float* __restrict__ yi,
                                              const float* __restrict__ a_sm,
                                              const float* __restrict__ W,
                                              const float* __restrict__ b,
                                              float* __restrict__ C,
                                              int d, int K) {
    __shared__ float As[16][64];
    __shared__ float Bs[16][64];
    int bn = blockIdx.x * 64, bm = blockIdx.y * 64;
    int tid = threadIdx.x;
    int tx = tid & 15, ty = tid >> 4;
    float a0 = a_sm[0], a1 = a_sm[1], a2 = a_sm[2], a3 = a_sm[3];
    float acc[4][4] = {};
    int ar = tid >> 2, aq = (tid & 3) * 4;    // A stage: row ar, k-quad aq
    int bk = tid >> 4, nq = (tid & 15) * 4;   // B stage
    for (int k0 = 0; k0 < K; k0 += 16) {
        int row = bm + ar;
        #pragma unroll
        for (int q = 0; q < 4; ++q) {
            int k = k0 + aq + q;
            float av;
            if (k < d) {
                av = a0 * hop[(size_t)row*d + k];
            } else {
                int c = k - d;
                if (c < 32)      av = a1 * yo[(size_t)row*NC + c];
                else if (c < 64) av = a2 * yi[(size_t)row*NC + c - 32];
                else             av = a3 * (yo[(size_t)row*NC + c - 64] + yi[(size_t)row*NC + c - 64]);
            }
            As[aq + q][ar] = av;
        }
        float4 bv = *reinterpret_cast<const float4*>(&W[(size_t)(k0 + bk)*NH + bn + nq]);
        Bs[bk][nq+0] = bv.x; Bs[bk][nq+1] = bv.y; Bs[bk][nq+2] = bv.z; Bs[bk][nq+3] = bv.w;
        __syncthreads();
        #pragma unroll
        for (int kk = 0; kk < 16; ++kk) {
            float ra[4], rb[4];
            #pragma unroll
            for (int j = 0; j < 4; ++j) ra[j] = As[kk][ty*4 + j];
            #pragma unroll
            for (int j = 0; j < 4; ++j) rb[j] = Bs[kk][tx*4 + j];
            #pragma unroll
            for (int x = 0; x < 4; ++x)
                #pragma unroll
                for (int yj = 0; yj < 4; ++yj) acc[x][yj] += ra[x] * rb[yj];
        }
        __syncthreads();
    }
    #pragma unroll
    for (int x = 0; x < 4; ++x) {
        int r = bm + ty*4 + x;
        #pragma unroll
        for (int yj = 0; yj < 4; ++yj) {
            int cc = bn + tx*4 + yj;
            C[(size_t)r*NH + cc] = acc[x][yj] + b[cc];
        }
    }
}

// ---------------- row l2norm + feats write + running max ----------------
__global__ void k_l2norm(const float* __restrict__ tmp, float* __restrict__ feats,
                         float* __restrict__ maxf, const int* __restrict__ lnflag,
                         int first) {
    int i = blockIdx.x;
    int t = threadIdx.x; // 256
    float v0 = tmp[(size_t)i*NH + t];
    float v1 = tmp[(size_t)i*NH + 256 + t];
    float ss = v0*v0 + v1*v1;
    __shared__ float red[4];
    #pragma unroll
    for (int o = 32; o > 0; o >>= 1) ss += __shfl_down(ss, o, 64);
    if ((t & 63) == 0) red[t >> 6] = ss;
    __syncthreads();
    float tot = red[0] + red[1] + red[2] + red[3];
    float scale = 1.0f;
    if (*lnflag) {
        float n = sqrtf(tot);
        scale = 1.0f / fmaxf(n, 1e-12f);
    }
    v0 *= scale; v1 *= scale;
    feats[(size_t)i*NH + t] = v0;
    feats[(size_t)i*NH + 256 + t] = v1;
    if (first) {
        maxf[(size_t)i*NH + t] = v0;
        maxf[(size_t)i*NH + 256 + t] = v1;
    } else {
        maxf[(size_t)i*NH + t] = fmaxf(maxf[(size_t)i*NH + t], v0);
        maxf[(size_t)i*NH + 256 + t] = fmaxf(maxf[(size_t)i*NH + 256 + t], v1);
    }
}

// ---------------- final: relu(concat) @ W2 + b2 -> log_softmax ----------------
__global__ void k_final(const float* __restrict__ feat0, const float* __restrict__ maxf,
                        const float* __restrict__ W2, const float* __restrict__ b2,
                        float* __restrict__ out) {
    int i = blockIdx.x;
    int t = threadIdx.x; // 256
    __shared__ float row[NF + NH];
    __shared__ float lg[NC];
    __shared__ float lse;
    for (int c = t; c < NF; c += 256) row[c] = fmaxf(feat0[(size_t)i*NF + c], 0.f);
    for (int c = t; c < NH; c += 256) row[NF + c] = fmaxf(maxf[(size_t)i*NH + c], 0.f);
    __syncthreads();
    if (t < NC) {
        float acc = b2[t];
        for (int k = 0; k < NF + NH; ++k) acc += row[k] * W2[(size_t)k*NC + t];
        lg[t] = acc;
    }
    __syncthreads();
    if (t == 0) {
        float m = lg[0];
        for (int c = 1; c < NC; ++c) m = fmaxf(m, lg[c]);
        float s = 0.f;
        for (int c = 0; c < NC; ++c) s += expf(lg[c] - m);
        lse = m + logf(s);
    }
    __syncthreads();
    if (t < NC) out[(size_t)i*NC + t] = lg[t] - lse;
}

extern "C" void kernel_launch(void* const* d_in, const int* in_sizes, int n_in,
                              void* d_out, int out_size, void* d_ws, size_t ws_size,
                              hipStream_t stream) {
    const float* adj      = (const float*)d_in[0];
    const float* features = (const float*)d_in[1];
    const float* y        = (const float*)d_in[2];
    const float* W0       = (const float*)d_in[3];
    const float* b0       = (const float*)d_in[4];
    const float* W1_0     = (const float*)d_in[5];
    const float* b1_0     = (const float*)d_in[6];
    const float* W1_1     = (const float*)d_in[7];
    const float* b1_1     = (const float*)d_in[8];
    const float* W2       = (const float*)d_in[9];
    const float* b2       = (const float*)d_in[10];
    const float* alphas   = (const float*)d_in[11];
    const int*   lnflag   = (const int*)d_in[12];
    float* out = (float*)d_out;

    char* ws = (char*)d_ws;
    size_t off = 0;
    auto alloc = [&](size_t bytes) -> char* {
        char* p = ws + off;
        off = (off + bytes + 255) & ~(size_t)255;
        return p;
    };
    float* a_sm  = (float*)alloc(16 * 4);
    int*   rowcnt = (int*)alloc((size_t)NN * 4);
    int*   rowptr = (int*)alloc((size_t)(NN + 1) * 4);
    int*   colidx = (int*)alloc((size_t)262144 * 4);
    float* vals   = (float*)alloc((size_t)262144 * 4);
    u64* B1  = (u64*)alloc((size_t)NN * 64 * 8);
    u64* B2  = (u64*)alloc((size_t)NN * 64 * 8);
    u64* B4  = (u64*)alloc((size_t)NN * 64 * 8);
    u64* B1T = (u64*)alloc((size_t)NN * 64 * 8);
    u64* B2T = (u64*)alloc((size_t)NN * 64 * 8);
    u64* B4T = (u64*)alloc((size_t)NN * 64 * 8);
    u64* LC  = (u64*)alloc((size_t)NC * 64 * 8);
    float* yout = (float*)alloc((size_t)NN * NC * 4);
    float* yin  = (float*)alloc((size_t)NN * NC * 4);
    float* bufA = (float*)alloc((size_t)NN * NF * 4);
    float* bufB = (float*)alloc((size_t)NN * NF * 4);
    float* feats = (float*)alloc((size_t)NN * NH * 4);
    float* maxf  = (float*)alloc((size_t)NN * NH * 4);
    float* tmpo  = (float*)alloc((size_t)NN * NH * 4);

    // setup
    k_alpha<<<1, 64, 0, stream>>>(alphas, a_sm);
    k_bits_count<<<NN, 64, 0, stream>>>(adj, B1, rowcnt);
    k_scan<<<1, 1024, 0, stream>>>(rowcnt, rowptr);
    k_fill<<<NN, 64, 0, stream>>>(adj, rowptr, colidx, vals);
    hipMemsetAsync(LC, 0, (size_t)NC * 64 * 8, stream);
    k_labelbits<<<NN / 256, 256, 0, stream>>>(y, LC);
    k_bsquare<<<NN, 64, 0, stream>>>(B1, B1, B2);
    k_bsquare<<<NN, 64, 0, stream>>>(B2, B2, B4);
    dim3 tg(64, 64);
    k_btrans<<<tg, 64, 0, stream>>>(B1, B1T);
    k_btrans<<<tg, 64, 0, stream>>>(B2, B2T);
    k_btrans<<<tg, 64, 0, stream>>>(B4, B4T);

    dim3 g1024(NF / 256, NN);
    dim3 g512(NH / 256, NN);
    dim3 gg(NH / 64, NN / 64);

    // ---- layer 0: pow = adj, d = 1024, K = 1120 ----
    k_ydist<<<NN, 64, 0, stream>>>(B1, LC, yout);
    k_ydist<<<NN, 64, 0, stream>>>(B1T, LC, yin);
    k_spmm<<<g1024, 256, 0, stream>>>(rowptr, colidx, vals, features, bufA, NF);
    k_gemm<<<gg, 256, 0, stream>>>(bufA, yout, yin, a_sm + 0, W0, b0, tmpo, NF, NF + 3*NC);
    k_l2norm<<<NN, 256, 0, stream>>>(tmpo, feats, maxf, lnflag, 1);

    // ---- layer 1: pow = adj^2, d = 512, K = 608 ----
    k_ydist<<<NN, 64, 0, stream>>>(B2, LC, yout);
    k_ydist<<<NN, 64, 0, stream>>>(B2T, LC, yin);
    k_spmm<<<g512, 256, 0, stream>>>(rowptr, colidx, vals, feats, bufB, NH);
    k_spmm<<<g512, 256, 0, stream>>>(rowptr, colidx, vals, bufB, bufA, NH);
    k_gemm<<<gg, 256, 0, stream>>>(bufA, yout, yin, a_sm + 5, W1_0, b1_0, tmpo, NH, NH + 3*NC);
    k_l2norm<<<NN, 256, 0, stream>>>(tmpo, feats, maxf, lnflag, 0);

    // ---- layer 2: pow = adj^4, d = 512, K = 608 ----
    k_ydist<<<NN, 64, 0, stream>>>(B4, LC, yout);
    k_ydist<<<NN, 64, 0, stream>>>(B4T, LC, yin);
    k_spmm<<<g512, 256, 0, stream>>>(rowptr, colidx, vals, feats, bufB, NH);
    k_spmm<<<g512, 256, 0, stream>>>(rowptr, colidx, vals, bufB, bufA, NH);
    k_spmm<<<g512, 256, 0, stream>>>(rowptr, colidx, vals, bufA, bufB, NH);
    k_spmm<<<g512, 256, 0, stream>>>(rowptr, colidx, vals, bufB, bufA, NH);
    k_gemm<<<gg, 256, 0, stream>>>(bufA, yout, yin, a_sm + 10, W1_1, b1_1, tmpo, NH, NH + 3*NC);
    k_l2norm<<<NN, 256, 0, stream>>>(tmpo, feats, maxf, lnflag, 0);

    // ---- final ----
    k_final<<<NN, 256, 0, stream>>>(features, maxf, W2, b2, out);
}

// Round 2
// 358.520 us; speedup vs baseline: 1.8714x; 1.8714x over previous
//
#include <hip/hip_runtime.h>
#include <hip/hip_bf16.h>
#include <math.h>

typedef unsigned long long u64;
typedef unsigned short ushort_t;
typedef float f32x4 __attribute__((ext_vector_type(4)));
typedef short s16x8 __attribute__((ext_vector_type(8)));

#define NN 4096
#define NF 1024
#define NH 512
#define NC 32
#define LDP 40  // padded LDS row stride (bf16 elems) for MFMA tiles

__device__ inline float bf2f(ushort_t u) {
    unsigned int v = ((unsigned int)u) << 16;
    return __uint_as_float(v);
}
__device__ inline ushort_t f2bf(float f) {
    __hip_bfloat16 h = __float2bfloat16(f);
    return *(ushort_t*)&h;
}

// ---------------- alphas softmax (3 rows of 5) ----------------
__global__ void k_alpha(const float* __restrict__ alphas, float* __restrict__ a_sm) {
    if (blockIdx.x == 0 && threadIdx.x == 0) {
        for (int i = 0; i < 3; ++i) {
            float m = -1e30f;
            for (int j = 0; j < 5; ++j) m = fmaxf(m, alphas[i*5+j]);
            float e[5]; float s = 0.f;
            for (int j = 0; j < 5; ++j) { e[j] = expf(alphas[i*5+j] - m); s += e[j]; }
            for (int j = 0; j < 5; ++j) a_sm[i*5+j] = e[j] / s;
        }
    }
}

// ---------------- fused: B1 bitset + ELL CSR (single adj pass) ----------------
// one wave per row; ballot-ordered -> deterministic, column-sorted
__global__ void k_build(const float* __restrict__ adj, u64* __restrict__ B1,
                        int* __restrict__ rowcnt, int* __restrict__ colidx,
                        float* __restrict__ vals) {
    int i = blockIdx.x;
    int lane = threadIdx.x;
    const float* row = adj + (size_t)i * NN;
    u64 myword = 0;
    int pos = 0;
    for (int j = 0; j < 64; ++j) {
        float v = row[j*64 + lane];
        u64 m = __ballot(v > 0.0f);
        if (j == lane) myword = m;
        if (v > 0.0f) {
            int off = __popcll(m & ((1ULL << lane) - 1ULL));
            int s = pos + off;
            if (s < 64) { colidx[i*64 + s] = j*64 + lane; vals[i*64 + s] = v; }
        }
        pos += __popcll(m);
    }
    B1[(size_t)i*64 + lane] = myword;
    if (lane == 0) rowcnt[i] = pos < 64 ? pos : 64;
}

// ---------------- per-class label bitsets from one-hot y ----------------
__global__ void k_labelbits(const float* __restrict__ y, u64* __restrict__ L) {
    int j = blockIdx.x * blockDim.x + threadIdx.x;
    if (j >= NN) return;
    for (int c = 0; c < NC; ++c) {
        if (y[(size_t)j*NC + c] > 0.5f)
            atomicOr(&L[c*64 + (j >> 6)], 1ULL << (j & 63));
    }
}

// ---------------- boolean matrix product: Bout[i] = OR_{k in bits(Bidx[i])} Bdat[k] ----------------
__global__ void k_bsquare(const u64* __restrict__ Bidx, const u64* __restrict__ Bdat,
                          u64* __restrict__ Bout) {
    int i = blockIdx.x;
    int t = threadIdx.x; // 64
    __shared__ u64 ridx[64];
    ridx[t] = Bidx[(size_t)i*64 + t];
    __syncthreads();
    u64 acc = 0;
    for (int u = 0; u < 64; ++u) {
        u64 w = ridx[u];
        while (w) {
            int k = u*64 + (__ffsll((unsigned long long)w) - 1);
            acc |= Bdat[(size_t)k*64 + t];
            w &= (w - 1);
        }
    }
    Bout[(size_t)i*64 + t] = acc;
}

// ---------------- 64x64-tile bit transpose ----------------
__global__ void k_btrans(const u64* __restrict__ B, u64* __restrict__ BT) {
    int I = blockIdx.x, J = blockIdx.y;
    int t = threadIdx.x; // 64
    __shared__ u64 ld[64];
    ld[t] = B[(size_t)(I*64 + t)*64 + J];
    __syncthreads();
    u64 out = 0;
    for (int r = 0; r < 64; ++r) out |= ((ld[r] >> t) & 1ULL) << r;
    BT[(size_t)(J*64 + t)*64 + I] = out;
}

// ---------------- y columns of mat via popcount: cols [d, d+96) ----------------
__global__ void k_ymat(const u64* __restrict__ B, const u64* __restrict__ BT,
                       const u64* __restrict__ LC, const float* __restrict__ asp,
                       __hip_bfloat16* __restrict__ mat, int d, int K) {
    int i = blockIdx.x;
    int t = threadIdx.x; // 64
    __shared__ u64 row[64], rowT[64];
    __shared__ float sy[64];
    row[t]  = B[(size_t)i*64 + t];
    rowT[t] = BT[(size_t)i*64 + t];
    __syncthreads();
    int c = t & 31;
    const u64* Lc = LC + c*64;
    int cnt = 0;
    if (t < 32) { for (int w = 0; w < 64; ++w) cnt += __popcll(row[w]  & Lc[w]); }
    else        { for (int w = 0; w < 64; ++w) cnt += __popcll(rowT[w] & Lc[w]); }
    sy[t] = (float)cnt;
    __syncthreads();
    if (t < 32) {
        float a1 = asp[1], a2 = asp[2], a3 = asp[3];
        float yo = sy[t], yi = sy[t + 32];
        ushort_t* m = (ushort_t*)mat;
        m[(size_t)i*K + d + t]      = f2bf(a1 * yo);
        m[(size_t)i*K + d + 32 + t] = f2bf(a2 * yi);
        m[(size_t)i*K + d + 64 + t] = f2bf(a3 * (yo + yi));
    }
}

// ---------------- SpMM (ELL): Y[i,:] = alpha * sum_p vals[i,p] * X[col,:], bf16 in/out ----------------
// block = d/2 threads, one block per row; each thread handles 2 columns
__global__ void k_spmm(const int* __restrict__ rowcnt, const int* __restrict__ colidx,
                       const float* __restrict__ vals, const __hip_bfloat16* __restrict__ X,
                       __hip_bfloat16* __restrict__ Y, int d, int ystride,
                       const float* __restrict__ a_sm, int ai) {
    int i = blockIdx.x;
    int t = threadIdx.x;
    int cnt = rowcnt[i];
    float acc0 = 0.f, acc1 = 0.f;
    const ushort_t* Xu = (const ushort_t*)X;
    for (int p = 0; p < cnt; ++p) {
        int col = colidx[i*64 + p];
        float v = vals[i*64 + p];
        ushort2 xv = *(const ushort2*)&Xu[(size_t)col * d + 2*t];
        acc0 += v * bf2f(xv.x);
        acc1 += v * bf2f(xv.y);
    }
    float alpha = (ai >= 0) ? a_sm[ai] : 1.0f;
    ushort2 o;
    o.x = f2bf(alpha * acc0);
    o.y = f2bf(alpha * acc1);
    *(ushort2*)&((ushort_t*)Y)[(size_t)i*ystride + 2*t] = o;
}

// ---------------- convert features fp32 -> bf16 ----------------
__global__ void k_featbf(const float* __restrict__ f, __hip_bfloat16* __restrict__ o) {
    int base = blockIdx.x * 1024 + threadIdx.x * 4;
    float4 v = *(const float4*)&f[base];
    ushort_t* ou = (ushort_t*)o;
    ushort4 w;
    w.x = f2bf(v.x); w.y = f2bf(v.y); w.z = f2bf(v.z); w.w = f2bf(v.w);
    *(ushort4*)&ou[base] = w;
}

// ---------------- transpose W [K][NH] fp32 -> Wt [NH][K] bf16 ----------------
__global__ void k_wt(const float* __restrict__ W, __hip_bfloat16* __restrict__ Wt, int K) {
    __shared__ float tile[32][33];
    int kb = blockIdx.x * 32, nb = blockIdx.y * 32;
    int tc = threadIdx.x & 31, tr8 = threadIdx.x >> 5; // 256 threads
    for (int r = tr8; r < 32; r += 8)
        tile[r][tc] = W[(size_t)(kb + r) * NH + nb + tc];
    __syncthreads();
    ushort_t* Wu = (ushort_t*)Wt;
    for (int r = tr8; r < 32; r += 8)
        Wu[(size_t)(nb + r) * K + kb + tc] = f2bf(tile[tc][r]);
}

// ---------------- MFMA GEMM: C[NN][NH] fp32 = mat[NN][K] bf16 @ Wt[NH][K]^T + b ----------------
// 64x64 tile, BK=32, 4 waves (each 16 rows x 64 cols), XCD-swizzled grid of 512
__global__ __launch_bounds__(256) void k_gemm_mfma(const __hip_bfloat16* __restrict__ mat,
                                                   const __hip_bfloat16* __restrict__ Wt,
                                                   const float* __restrict__ b,
                                                   float* __restrict__ C, int K) {
    __shared__ ushort_t As[64 * LDP];
    __shared__ ushort_t Bs[64 * LDP];
    int bx = blockIdx.x;                 // 0..511
    int xcd = bx & 7, rest = bx >> 3;
    int nt = rest & 7, mt = (rest >> 3) * 8 + xcd; // bijective: all nt of an mt on one XCD
    int bm = mt * 64, bn = nt * 64;
    int tid = threadIdx.x;
    int srow = tid >> 2, scol = (tid & 3) * 8;     // staging: 16B per thread per tile
    int wid = tid >> 6, lane = tid & 63;
    int fr = lane & 15, fk = (lane >> 4) * 8;
    f32x4 acc[4] = {{0,0,0,0},{0,0,0,0},{0,0,0,0},{0,0,0,0}};
    const ushort_t* Au = (const ushort_t*)mat + (size_t)(bm + srow) * K + scol;
    const ushort_t* Bu = (const ushort_t*)Wt  + (size_t)(bn + srow) * K + scol;
    for (int k0 = 0; k0 < K; k0 += 32) {
        *(s16x8*)&As[srow * LDP + scol] = *(const s16x8*)(Au + k0);
        *(s16x8*)&Bs[srow * LDP + scol] = *(const s16x8*)(Bu + k0);
        __syncthreads();
        s16x8 af = *(const s16x8*)&As[(wid * 16 + fr) * LDP + fk];
        #pragma unroll
        for (int j = 0; j < 4; ++j) {
            s16x8 bfv = *(const s16x8*)&Bs[(j * 16 + fr) * LDP + fk];
            acc[j] = __builtin_amdgcn_mfma_f32_16x16x32_bf16(af, bfv, acc[j], 0, 0, 0);
        }
        __syncthreads();
    }
    int drow = bm + wid * 16 + (lane >> 4) * 4;
    #pragma unroll
    for (int j = 0; j < 4; ++j) {
        int col = bn + j * 16 + fr;
        float bias = b[col];
        #pragma unroll
        for (int r = 0; r < 4; ++r)
            C[(size_t)(drow + r) * NH + col] = acc[j][r] + bias;
    }
}

// ---------------- row l2norm; write feats bf16 + running max fp32 ----------------
__global__ void k_l2norm(const float* __restrict__ tmp, __hip_bfloat16* __restrict__ featsb,
                         float* __restrict__ maxf, const int* __restrict__ lnflag,
                         int first) {
    int i = blockIdx.x;
    int t = threadIdx.x; // 256
    float v0 = tmp[(size_t)i*NH + t];
    float v1 = tmp[(size_t)i*NH + 256 + t];
    float ss = v0*v0 + v1*v1;
    __shared__ float red[4];
    #pragma unroll
    for (int o = 32; o > 0; o >>= 1) ss += __shfl_down(ss, o, 64);
    if ((t & 63) == 0) red[t >> 6] = ss;
    __syncthreads();
    float tot = red[0] + red[1] + red[2] + red[3];
    float scale = 1.0f;
    if (*lnflag) {
        float n = sqrtf(tot);
        scale = 1.0f / fmaxf(n, 1e-12f);
    }
    v0 *= scale; v1 *= scale;
    ushort_t* fb = (ushort_t*)featsb;
    fb[(size_t)i*NH + t]       = f2bf(v0);
    fb[(size_t)i*NH + 256 + t] = f2bf(v1);
    if (first) {
        maxf[(size_t)i*NH + t] = v0;
        maxf[(size_t)i*NH + 256 + t] = v1;
    } else {
        maxf[(size_t)i*NH + t] = fmaxf(maxf[(size_t)i*NH + t], v0);
        maxf[(size_t)i*NH + 256 + t] = fmaxf(maxf[(size_t)i*NH + 256 + t], v1);
    }
}

// ---------------- final: relu(concat) @ W2 + b2 -> log_softmax; 8 rows/block ----------------
__global__ __launch_bounds__(256) void k_final(const float* __restrict__ feat0,
                                               const float* __restrict__ maxf,
                                               const float* __restrict__ W2,
                                               const float* __restrict__ b2,
                                               float* __restrict__ out) {
    int rb = blockIdx.x * 8;
    int t = threadIdx.x; // 256
    __shared__ float rows[8][NF + NH];
    __shared__ float part[8][8][32]; // [kgroup][row][class]
    for (int r = 0; r < 8; ++r) {
        const float* f0 = feat0 + (size_t)(rb + r) * NF;
        for (int c = t; c < NF; c += 256) rows[r][c] = fmaxf(f0[c], 0.f);
        const float* mf = maxf + (size_t)(rb + r) * NH;
        for (int c = t; c < NH; c += 256) rows[r][NF + c] = fmaxf(mf[c], 0.f);
    }
    __syncthreads();
    int c = t & 31, g = t >> 5; // 8 k-groups of 192
    float acc[8] = {0,0,0,0,0,0,0,0};
    for (int k = g * 192; k < (g + 1) * 192; ++k) {
        float w = W2[(size_t)k * NC + c];
        #pragma unroll
        for (int r = 0; r < 8; ++r) acc[r] += rows[r][k] * w;
    }
    #pragma unroll
    for (int r = 0; r < 8; ++r) part[g][r][c] = acc[r];
    __syncthreads();
    int r = g;
    float lg = b2[c];
    #pragma unroll
    for (int gg = 0; gg < 8; ++gg) lg += part[gg][r][c];
    float m = lg;
    #pragma unroll
    for (int o = 16; o > 0; o >>= 1) m = fmaxf(m, __shfl_xor(m, o, 32));
    float e = expf(lg - m), s = e;
    #pragma unroll
    for (int o = 16; o > 0; o >>= 1) s += __shfl_xor(s, o, 32);
    out[(size_t)(rb + r) * NC + c] = lg - m - logf(s);
}

extern "C" void kernel_launch(void* const* d_in, const int* in_sizes, int n_in,
                              void* d_out, int out_size, void* d_ws, size_t ws_size,
                              hipStream_t stream) {
    const float* adj      = (const float*)d_in[0];
    const float* features = (const float*)d_in[1];
    const float* y        = (const float*)d_in[2];
    const float* W0       = (const float*)d_in[3];
    const float* b0       = (const float*)d_in[4];
    const float* W1_0     = (const float*)d_in[5];
    const float* b1_0     = (const float*)d_in[6];
    const float* W1_1     = (const float*)d_in[7];
    const float* b1_1     = (const float*)d_in[8];
    const float* W2       = (const float*)d_in[9];
    const float* b2       = (const float*)d_in[10];
    const float* alphas   = (const float*)d_in[11];
    const int*   lnflag   = (const int*)d_in[12];
    float* out = (float*)d_out;

    char* ws = (char*)d_ws;
    size_t off = 0;
    auto alloc = [&](size_t bytes) -> char* {
        char* p = ws + off;
        off = (off + bytes + 255) & ~(size_t)255;
        return p;
    };
    float* a_sm   = (float*)alloc(16 * 4);
    int*   rowcnt = (int*)alloc((size_t)NN * 4);
    int*   colidx = (int*)alloc((size_t)NN * 64 * 4);
    float* vals   = (float*)alloc((size_t)NN * 64 * 4);
    u64* B1  = (u64*)alloc((size_t)NN * 64 * 8);
    u64* B2  = (u64*)alloc((size_t)NN * 64 * 8);
    u64* B4  = (u64*)alloc((size_t)NN * 64 * 8);
    u64* B1T = (u64*)alloc((size_t)NN * 64 * 8);
    u64* B2T = (u64*)alloc((size_t)NN * 64 * 8);
    u64* B4T = (u64*)alloc((size_t)NN * 64 * 8);
    u64* LC  = (u64*)alloc((size_t)NC * 64 * 8);
    __hip_bfloat16* featb  = (__hip_bfloat16*)alloc((size_t)NN * NF * 2);
    __hip_bfloat16* featsb = (__hip_bfloat16*)alloc((size_t)NN * NH * 2);
    __hip_bfloat16* t1b    = (__hip_bfloat16*)alloc((size_t)NN * NH * 2);
    __hip_bfloat16* t2b    = (__hip_bfloat16*)alloc((size_t)NN * NH * 2);
    __hip_bfloat16* mat    = (__hip_bfloat16*)alloc((size_t)NN * (NF + 96) * 2);
    __hip_bfloat16* Wtb    = (__hip_bfloat16*)alloc((size_t)NH * (NF + 96) * 2);
    float* tmpo = (float*)alloc((size_t)NN * NH * 4);
    float* maxf = (float*)alloc((size_t)NN * NH * 4);

    const int K0 = NF + 3*NC;  // 1120
    const int K1 = NH + 3*NC;  // 608

    // setup
    k_alpha<<<1, 64, 0, stream>>>(alphas, a_sm);
    k_build<<<NN, 64, 0, stream>>>(adj, B1, rowcnt, colidx, vals);
    hipMemsetAsync(LC, 0, (size_t)NC * 64 * 8, stream);
    k_labelbits<<<NN / 256, 256, 0, stream>>>(y, LC);
    k_bsquare<<<NN, 64, 0, stream>>>(B1, B1, B2);
    k_bsquare<<<NN, 64, 0, stream>>>(B2, B2, B4);
    dim3 tg(64, 64);
    k_btrans<<<tg, 64, 0, stream>>>(B1, B1T);
    k_btrans<<<tg, 64, 0, stream>>>(B2, B2T);
    k_btrans<<<tg, 64, 0, stream>>>(B4, B4T);
    k_featbf<<<NN, 256, 0, stream>>>(features, featb);

    // ---- layer 0: pow = adj, d = 1024, K = 1120 ----
    k_ymat<<<NN, 64, 0, stream>>>(B1, B1T, LC, a_sm + 0, mat, NF, K0);
    k_spmm<<<NN, NF/2, 0, stream>>>(rowcnt, colidx, vals, featb, mat, NF, K0, a_sm, 0);
    k_wt<<<dim3(K0/32, 16), 256, 0, stream>>>(W0, Wtb, K0);
    k_gemm_mfma<<<512, 256, 0, stream>>>(mat, Wtb, b0, tmpo, K0);
    k_l2norm<<<NN, 256, 0, stream>>>(tmpo, featsb, maxf, lnflag, 1);

    // ---- layer 1: pow = adj^2, d = 512, K = 608 ----
    k_ymat<<<NN, 64, 0, stream>>>(B2, B2T, LC, a_sm + 5, mat, NH, K1);
    k_spmm<<<NN, NH/2, 0, stream>>>(rowcnt, colidx, vals, featsb, t1b, NH, NH, a_sm, -1);
    k_spmm<<<NN, NH/2, 0, stream>>>(rowcnt, colidx, vals, t1b, mat, NH, K1, a_sm, 5);
    k_wt<<<dim3(K1/32, 16), 256, 0, stream>>>(W1_0, Wtb, K1);
    k_gemm_mfma<<<512, 256, 0, stream>>>(mat, Wtb, b1_0, tmpo, K1);
    k_l2norm<<<NN, 256, 0, stream>>>(tmpo, featsb, maxf, lnflag, 0);

    // ---- layer 2: pow = adj^4, d = 512, K = 608 ----
    k_ymat<<<NN, 64, 0, stream>>>(B4, B4T, LC, a_sm + 10, mat, NH, K1);
    k_spmm<<<NN, NH/2, 0, stream>>>(rowcnt, colidx, vals, featsb, t1b, NH, NH, a_sm, -1);
    k_spmm<<<NN, NH/2, 0, stream>>>(rowcnt, colidx, vals, t1b, t2b, NH, NH, a_sm, -1);
    k_spmm<<<NN, NH/2, 0, stream>>>(rowcnt, colidx, vals, t2b, t1b, NH, NH, a_sm, -1);
    k_spmm<<<NN, NH/2, 0, stream>>>(rowcnt, colidx, vals, t1b, mat, NH, K1, a_sm, 10);
    k_wt<<<dim3(K1/32, 16), 256, 0, stream>>>(W1_1, Wtb, K1);
    k_gemm_mfma<<<512, 256, 0, stream>>>(mat, Wtb, b1_1, tmpo, K1);
    k_l2norm<<<NN, 256, 0, stream>>>(tmpo, featsb, maxf, lnflag, 0);

    // ---- final ----
    k_final<<<NN / 8, 256, 0, stream>>>(features, maxf, W2, b2, out);
}

// Round 3
// 309.734 us; speedup vs baseline: 2.1662x; 1.1575x over previous
//
#include <hip/hip_runtime.h>
#include <hip/hip_bf16.h>
#include <math.h>

typedef unsigned long long u64;
typedef unsigned short ushort_t;
typedef float f32x4 __attribute__((ext_vector_type(4)));
typedef short s16x8 __attribute__((ext_vector_type(8)));

#define NN 4096
#define NF 1024
#define NH 512
#define NC 32
#define LDP 40  // padded LDS row stride (bf16 elems) for MFMA tiles
#define K0 (NF + 3*NC)  // 1120
#define K1 (NH + 3*NC)  // 608

__device__ inline float bf2f(ushort_t u) {
    unsigned int v = ((unsigned int)u) << 16;
    return __uint_as_float(v);
}
__device__ inline ushort_t f2bf(float f) {
    __hip_bfloat16 h = __float2bfloat16(f);
    return *(ushort_t*)&h;
}

// ---------------- fused build: B1 bitset + ELL (single adj pass, no ballots) ----------------
// one wave per row; lane l owns bit-word l (columns 64l..64l+63)
__global__ __launch_bounds__(64) void k_build(const float* __restrict__ adj, u64* __restrict__ B1,
                                              int* __restrict__ rowcnt, int* __restrict__ colidx,
                                              float* __restrict__ vals) {
    int i = blockIdx.x;
    int l = threadIdx.x; // 64
    const float* row = adj + (size_t)i * NN + l * 64;
    const float4* row4 = (const float4*)row;
    u64 w = 0;
    #pragma unroll
    for (int k = 0; k < 16; ++k) {
        float4 v = row4[k];
        if (v.x > 0.f) w |= 1ULL << (4*k + 0);
        if (v.y > 0.f) w |= 1ULL << (4*k + 1);
        if (v.z > 0.f) w |= 1ULL << (4*k + 2);
        if (v.w > 0.f) w |= 1ULL << (4*k + 3);
    }
    B1[(size_t)i*64 + l] = w;
    int cnt = __popcll(w);
    // inclusive wave scan -> exclusive offset (column-sorted, deterministic)
    int pre = cnt;
    #pragma unroll
    for (int o = 1; o < 64; o <<= 1) {
        int u = __shfl_up(pre, o, 64);
        if (l >= o) pre += u;
    }
    int excl = pre - cnt;
    int total = __shfl(pre, 63, 64);
    u64 ww = w;
    int idx = excl;
    while (ww) {
        int b = __ffsll((unsigned long long)ww) - 1;
        ww &= ww - 1;
        if (idx < 64) {
            colidx[i*64 + idx] = l*64 + b;
            vals[i*64 + idx] = row[b];   // L1 hit
        }
        ++idx;
    }
    if (l == 0) rowcnt[i] = total < 64 ? total : 64;
}

// ---------------- fused prep: featbf | label bitsets | 3x W-transpose | alpha softmax ----------------
// roles by blockIdx.x range; 256 threads everywhere
__global__ __launch_bounds__(256) void k_prep(const float* __restrict__ features,
                                              __hip_bfloat16* __restrict__ featb,
                                              const float* __restrict__ y, u64* __restrict__ LC,
                                              const float* __restrict__ W0,
                                              const float* __restrict__ W1_0,
                                              const float* __restrict__ W1_1,
                                              __hip_bfloat16* __restrict__ Wt0,
                                              __hip_bfloat16* __restrict__ Wt1,
                                              __hip_bfloat16* __restrict__ Wt2,
                                              const float* __restrict__ alphas,
                                              float* __restrict__ a_sm) {
    __shared__ float tile[32][33];
    int b = blockIdx.x;
    int t = threadIdx.x;
    if (b < 4096) {
        // features fp32 -> bf16
        int base = b * 1024 + t * 4;
        float4 v = *(const float4*)&features[base];
        ushort4 o;
        o.x = f2bf(v.x); o.y = f2bf(v.y); o.z = f2bf(v.z); o.w = f2bf(v.w);
        *(ushort4*)&((ushort_t*)featb)[base] = o;
    } else if (b < 4112) {
        // label bitsets via ballot: word w covers rows w*64..w*64+63
        int w = (b - 4096) * 4 + (t >> 6);
        int l = t & 63;
        const float* yr = y + (size_t)(w*64 + l) * NC;
        for (int c = 0; c < NC; ++c) {
            u64 m = __ballot(yr[c] > 0.5f);
            if (l == c) LC[c*64 + w] = m;
        }
    } else {
        const float* W; __hip_bfloat16* Wt; int K, ktiles, idx;
        if (b < 4672)      { W = W0;   Wt = Wt0; K = K0; ktiles = 35; idx = b - 4112; }
        else if (b < 4976) { W = W1_0; Wt = Wt1; K = K1; ktiles = 19; idx = b - 4672; }
        else if (b < 5280) { W = W1_1; Wt = Wt2; K = K1; ktiles = 19; idx = b - 4976; }
        else {
            if (t == 0) {
                for (int i = 0; i < 3; ++i) {
                    float m = -1e30f;
                    for (int j = 0; j < 5; ++j) m = fmaxf(m, alphas[i*5+j]);
                    float e[5]; float s = 0.f;
                    for (int j = 0; j < 5; ++j) { e[j] = expf(alphas[i*5+j] - m); s += e[j]; }
                    for (int j = 0; j < 5; ++j) a_sm[i*5+j] = e[j] / s;
                }
            }
            return;
        }
        int kb = (idx % ktiles) * 32, nb = (idx / ktiles) * 32;
        int tc = t & 31, tr8 = t >> 5;
        for (int r = tr8; r < 32; r += 8)
            tile[r][tc] = W[(size_t)(kb + r) * NH + nb + tc];
        __syncthreads();
        ushort_t* Wu = (ushort_t*)Wt;
        for (int r = tr8; r < 32; r += 8)
            Wu[(size_t)(nb + r) * K + kb + tc] = f2bf(tile[tc][r]);
    }
}

// ---------------- boolean matrix product: Bout[i] = OR_{k in bits(Bidx[i])} Bdat[k] ----------------
__global__ void k_bsquare(const u64* __restrict__ Bidx, const u64* __restrict__ Bdat,
                          u64* __restrict__ Bout) {
    int i = blockIdx.x;
    int t = threadIdx.x; // 64
    __shared__ u64 ridx[64];
    ridx[t] = Bidx[(size_t)i*64 + t];
    __syncthreads();
    u64 acc = 0;
    for (int u = 0; u < 64; ++u) {
        u64 w = ridx[u];
        while (w) {
            int k = u*64 + (__ffsll((unsigned long long)w) - 1);
            acc |= Bdat[(size_t)k*64 + t];
            w &= (w - 1);
        }
    }
    Bout[(size_t)i*64 + t] = acc;
}

// ---------------- 64x64-tile bit transpose, all three matrices (grid.z) ----------------
__global__ void k_btrans(const u64* __restrict__ B1, const u64* __restrict__ B2,
                         const u64* __restrict__ B4, u64* __restrict__ B1T,
                         u64* __restrict__ B2T, u64* __restrict__ B4T) {
    const u64* B; u64* BT;
    switch (blockIdx.z) {
        case 0: B = B1; BT = B1T; break;
        case 1: B = B2; BT = B2T; break;
        default: B = B4; BT = B4T; break;
    }
    int I = blockIdx.x, J = blockIdx.y;
    int t = threadIdx.x; // 64
    __shared__ u64 ld[64];
    ld[t] = B[(size_t)(I*64 + t)*64 + J];
    __syncthreads();
    u64 out = 0;
    for (int r = 0; r < 64; ++r) out |= ((ld[r] >> t) & 1ULL) << r;
    BT[(size_t)(J*64 + t)*64 + I] = out;
}

// ---------------- y columns for all 3 layers via popcount (grid.y = layer) ----------------
__global__ void k_ymat(const u64* __restrict__ B1, const u64* __restrict__ B1T,
                       const u64* __restrict__ B2, const u64* __restrict__ B2T,
                       const u64* __restrict__ B4, const u64* __restrict__ B4T,
                       const u64* __restrict__ LC, const float* __restrict__ a_sm,
                       __hip_bfloat16* __restrict__ mat0, __hip_bfloat16* __restrict__ mat1,
                       __hip_bfloat16* __restrict__ mat2) {
    int layer = blockIdx.y;
    const u64 *B, *BT; const float* asp; ushort_t* m; int d, K;
    if (layer == 0)      { B = B1; BT = B1T; asp = a_sm;      m = (ushort_t*)mat0; d = NF; K = K0; }
    else if (layer == 1) { B = B2; BT = B2T; asp = a_sm + 5;  m = (ushort_t*)mat1; d = NH; K = K1; }
    else                 { B = B4; BT = B4T; asp = a_sm + 10; m = (ushort_t*)mat2; d = NH; K = K1; }
    int i = blockIdx.x;
    int t = threadIdx.x; // 64
    __shared__ u64 row[64], rowT[64];
    __shared__ float sy[64];
    row[t]  = B[(size_t)i*64 + t];
    rowT[t] = BT[(size_t)i*64 + t];
    __syncthreads();
    int c = t & 31;
    const u64* Lc = LC + c*64;
    int cnt = 0;
    if (t < 32) { for (int w = 0; w < 64; ++w) cnt += __popcll(row[w]  & Lc[w]); }
    else        { for (int w = 0; w < 64; ++w) cnt += __popcll(rowT[w] & Lc[w]); }
    sy[t] = (float)cnt;
    __syncthreads();
    if (t < 32) {
        float a1 = asp[1], a2 = asp[2], a3 = asp[3];
        float yo = sy[t], yi = sy[t + 32];
        m[(size_t)i*K + d + t]      = f2bf(a1 * yo);
        m[(size_t)i*K + d + 32 + t] = f2bf(a2 * yi);
        m[(size_t)i*K + d + 64 + t] = f2bf(a3 * (yo + yi));
    }
}

// ---------------- SpMM (ELL): one wave per row, ushort8 gathers ----------------
// blockDim = (d/8, 4); Y[i, 0..d) = alpha * sum_p vals[p] * X[col_p, :]
__global__ void k_spmm(const int* __restrict__ rowcnt, const int* __restrict__ colidx,
                       const float* __restrict__ vals, const __hip_bfloat16* __restrict__ X,
                       __hip_bfloat16* __restrict__ Y, int d, int ystride,
                       const float* __restrict__ a_sm, int ai) {
    int i = blockIdx.x * 4 + threadIdx.y;
    int t = threadIdx.x; // d/8
    int cnt = rowcnt[i];
    const ushort_t* Xu = (const ushort_t*)X;
    float acc[8] = {0,0,0,0,0,0,0,0};
    for (int p = 0; p < cnt; ++p) {
        int col = colidx[i*64 + p];
        float v = vals[i*64 + p];
        s16x8 xv = *(const s16x8*)&Xu[(size_t)col * d + 8*t];
        #pragma unroll
        for (int j = 0; j < 8; ++j) acc[j] += v * bf2f((ushort_t)xv[j]);
    }
    float alpha = (ai >= 0) ? a_sm[ai] : 1.0f;
    s16x8 o;
    #pragma unroll
    for (int j = 0; j < 8; ++j) o[j] = (short)f2bf(alpha * acc[j]);
    *(s16x8*)&((ushort_t*)Y)[(size_t)i*ystride + 8*t] = o;
}

// ---------------- MFMA GEMM: C[NN][NH] fp32 = mat[NN][K] bf16 @ Wt[NH][K]^T + b ----------------
// 64x64 tile, BK=32, 4 waves, XCD-swizzled grid of 512
__global__ __launch_bounds__(256) void k_gemm_mfma(const __hip_bfloat16* __restrict__ mat,
                                                   const __hip_bfloat16* __restrict__ Wt,
                                                   const float* __restrict__ b,
                                                   float* __restrict__ C, int K) {
    __shared__ ushort_t As[64 * LDP];
    __shared__ ushort_t Bs[64 * LDP];
    int bx = blockIdx.x;                 // 0..511
    int xcd = bx & 7, rest = bx >> 3;
    int nt = rest & 7, mt = (rest >> 3) * 8 + xcd; // all nt of an mt on one XCD
    int bm = mt * 64, bn = nt * 64;
    int tid = threadIdx.x;
    int srow = tid >> 2, scol = (tid & 3) * 8;
    int wid = tid >> 6, lane = tid & 63;
    int fr = lane & 15, fk = (lane >> 4) * 8;
    f32x4 acc[4] = {{0,0,0,0},{0,0,0,0},{0,0,0,0},{0,0,0,0}};
    const ushort_t* Au = (const ushort_t*)mat + (size_t)(bm + srow) * K + scol;
    const ushort_t* Bu = (const ushort_t*)Wt  + (size_t)(bn + srow) * K + scol;
    for (int k0 = 0; k0 < K; k0 += 32) {
        *(s16x8*)&As[srow * LDP + scol] = *(const s16x8*)(Au + k0);
        *(s16x8*)&Bs[srow * LDP + scol] = *(const s16x8*)(Bu + k0);
        __syncthreads();
        s16x8 af = *(const s16x8*)&As[(wid * 16 + fr) * LDP + fk];
        #pragma unroll
        for (int j = 0; j < 4; ++j) {
            s16x8 bfv = *(const s16x8*)&Bs[(j * 16 + fr) * LDP + fk];
            acc[j] = __builtin_amdgcn_mfma_f32_16x16x32_bf16(af, bfv, acc[j], 0, 0, 0);
        }
        __syncthreads();
    }
    int drow = bm + wid * 16 + (lane >> 4) * 4;
    #pragma unroll
    for (int j = 0; j < 4; ++j) {
        int col = bn + j * 16 + fr;
        float bias = b[col];
        #pragma unroll
        for (int r = 0; r < 4; ++r)
            C[(size_t)(drow + r) * NH + col] = acc[j][r] + bias;
    }
}

// ---------------- row l2norm; write feats bf16 + running max fp32 ----------------
__global__ void k_l2norm(const float* __restrict__ tmp, __hip_bfloat16* __restrict__ featsb,
                         float* __restrict__ maxf, const int* __restrict__ lnflag,
                         int first) {
    int i = blockIdx.x;
    int t = threadIdx.x; // 256
    float v0 = tmp[(size_t)i*NH + t];
    float v1 = tmp[(size_t)i*NH + 256 + t];
    float ss = v0*v0 + v1*v1;
    __shared__ float red[4];
    #pragma unroll
    for (int o = 32; o > 0; o >>= 1) ss += __shfl_down(ss, o, 64);
    if ((t & 63) == 0) red[t >> 6] = ss;
    __syncthreads();
    float tot = red[0] + red[1] + red[2] + red[3];
    float scale = 1.0f;
    if (*lnflag) {
        float n = sqrtf(tot);
        scale = 1.0f / fmaxf(n, 1e-12f);
    }
    v0 *= scale; v1 *= scale;
    ushort_t* fb = (ushort_t*)featsb;
    fb[(size_t)i*NH + t]       = f2bf(v0);
    fb[(size_t)i*NH + 256 + t] = f2bf(v1);
    if (first) {
        maxf[(size_t)i*NH + t] = v0;
        maxf[(size_t)i*NH + 256 + t] = v1;
    } else {
        maxf[(size_t)i*NH + t] = fmaxf(maxf[(size_t)i*NH + t], v0);
        maxf[(size_t)i*NH + 256 + t] = fmaxf(maxf[(size_t)i*NH + 256 + t], v1);
    }
}

// ---------------- final: relu(concat) @ W2 + b2 -> log_softmax; 8 rows/block ----------------
__global__ __launch_bounds__(256) void k_final(const float* __restrict__ feat0,
                                               const float* __restrict__ maxf,
                                               const float* __restrict__ W2,
                                               const float* __restrict__ b2,
                                               float* __restrict__ out) {
    int rb = blockIdx.x * 8;
    int t = threadIdx.x; // 256
    __shared__ float rows[8][NF + NH];
    __shared__ float part[8][8][32];
    for (int r = 0; r < 8; ++r) {
        const float* f0 = feat0 + (size_t)(rb + r) * NF;
        for (int c = t; c < NF; c += 256) rows[r][c] = fmaxf(f0[c], 0.f);
        const float* mf = maxf + (size_t)(rb + r) * NH;
        for (int c = t; c < NH; c += 256) rows[r][NF + c] = fmaxf(mf[c], 0.f);
    }
    __syncthreads();
    int c = t & 31, g = t >> 5;
    float acc[8] = {0,0,0,0,0,0,0,0};
    for (int k = g * 192; k < (g + 1) * 192; ++k) {
        float w = W2[(size_t)k * NC + c];
        #pragma unroll
        for (int r = 0; r < 8; ++r) acc[r] += rows[r][k] * w;
    }
    #pragma unroll
    for (int r = 0; r < 8; ++r) part[g][r][c] = acc[r];
    __syncthreads();
    int r = g;
    float lg = b2[c];
    #pragma unroll
    for (int gg = 0; gg < 8; ++gg) lg += part[gg][r][c];
    float m = lg;
    #pragma unroll
    for (int o = 16; o > 0; o >>= 1) m = fmaxf(m, __shfl_xor(m, o, 32));
    float e = expf(lg - m), s = e;
    #pragma unroll
    for (int o = 16; o > 0; o >>= 1) s += __shfl_xor(s, o, 32);
    out[(size_t)(rb + r) * NC + c] = lg - m - logf(s);
}

extern "C" void kernel_launch(void* const* d_in, const int* in_sizes, int n_in,
                              void* d_out, int out_size, void* d_ws, size_t ws_size,
                              hipStream_t stream) {
    const float* adj      = (const float*)d_in[0];
    const float* features = (const float*)d_in[1];
    const float* y        = (const float*)d_in[2];
    const float* W0       = (const float*)d_in[3];
    const float* b0       = (const float*)d_in[4];
    const float* W1_0     = (const float*)d_in[5];
    const float* b1_0     = (const float*)d_in[6];
    const float* W1_1     = (const float*)d_in[7];
    const float* b1_1     = (const float*)d_in[8];
    const float* W2       = (const float*)d_in[9];
    const float* b2       = (const float*)d_in[10];
    const float* alphas   = (const float*)d_in[11];
    const int*   lnflag   = (const int*)d_in[12];
    float* out = (float*)d_out;

    char* ws = (char*)d_ws;
    size_t off = 0;
    auto alloc = [&](size_t bytes) -> char* {
        char* p = ws + off;
        off = (off + bytes + 255) & ~(size_t)255;
        return p;
    };
    float* a_sm   = (float*)alloc(16 * 4);
    int*   rowcnt = (int*)alloc((size_t)NN * 4);
    int*   colidx = (int*)alloc((size_t)NN * 64 * 4);
    float* vals   = (float*)alloc((size_t)NN * 64 * 4);
    u64* B1  = (u64*)alloc((size_t)NN * 64 * 8);
    u64* B2  = (u64*)alloc((size_t)NN * 64 * 8);
    u64* B4  = (u64*)alloc((size_t)NN * 64 * 8);
    u64* B1T = (u64*)alloc((size_t)NN * 64 * 8);
    u64* B2T = (u64*)alloc((size_t)NN * 64 * 8);
    u64* B4T = (u64*)alloc((size_t)NN * 64 * 8);
    u64* LC  = (u64*)alloc((size_t)NC * 64 * 8);
    __hip_bfloat16* featb  = (__hip_bfloat16*)alloc((size_t)NN * NF * 2);
    __hip_bfloat16* featsb = (__hip_bfloat16*)alloc((size_t)NN * NH * 2);
    __hip_bfloat16* t1b    = (__hip_bfloat16*)alloc((size_t)NN * NH * 2);
    __hip_bfloat16* mat0   = (__hip_bfloat16*)alloc((size_t)NN * K0 * 2);
    __hip_bfloat16* mat1   = (__hip_bfloat16*)alloc((size_t)NN * K1 * 2);
    __hip_bfloat16* mat2   = (__hip_bfloat16*)alloc((size_t)NN * K1 * 2);
    __hip_bfloat16* Wt0    = (__hip_bfloat16*)alloc((size_t)NH * K0 * 2);
    __hip_bfloat16* Wt1    = (__hip_bfloat16*)alloc((size_t)NH * K1 * 2);
    __hip_bfloat16* Wt2    = (__hip_bfloat16*)alloc((size_t)NH * K1 * 2);
    float* tmpo = (float*)alloc((size_t)NN * NH * 4);
    float* maxf = (float*)alloc((size_t)NN * NH * 4);
    __hip_bfloat16* t2b = (__hip_bfloat16*)tmpo; // alias: dead ranges don't overlap in time

    // ---- setup ----
    k_build<<<NN, 64, 0, stream>>>(adj, B1, rowcnt, colidx, vals);
    k_prep<<<5281, 256, 0, stream>>>(features, featb, y, LC, W0, W1_0, W1_1,
                                     Wt0, Wt1, Wt2, alphas, a_sm);
    k_bsquare<<<NN, 64, 0, stream>>>(B1, B1, B2);
    k_bsquare<<<NN, 64, 0, stream>>>(B2, B2, B4);
    k_btrans<<<dim3(64, 64, 3), 64, 0, stream>>>(B1, B2, B4, B1T, B2T, B4T);
    k_ymat<<<dim3(NN, 3), 64, 0, stream>>>(B1, B1T, B2, B2T, B4, B4T, LC, a_sm,
                                           mat0, mat1, mat2);

    // ---- layer 0: pow = adj, d = 1024, K = 1120 ----
    k_spmm<<<NN/4, dim3(NF/8, 4), 0, stream>>>(rowcnt, colidx, vals, featb, mat0, NF, K0, a_sm, 0);
    k_gemm_mfma<<<512, 256, 0, stream>>>(mat0, Wt0, b0, tmpo, K0);
    k_l2norm<<<NN, 256, 0, stream>>>(tmpo, featsb, maxf, lnflag, 1);

    // ---- layer 1: pow = adj^2, d = 512, K = 608 ----
    k_spmm<<<NN/4, dim3(NH/8, 4), 0, stream>>>(rowcnt, colidx, vals, featsb, t1b, NH, NH, a_sm, -1);
    k_spmm<<<NN/4, dim3(NH/8, 4), 0, stream>>>(rowcnt, colidx, vals, t1b, mat1, NH, K1, a_sm, 5);
    k_gemm_mfma<<<512, 256, 0, stream>>>(mat1, Wt1, b1_0, tmpo, K1);
    k_l2norm<<<NN, 256, 0, stream>>>(tmpo, featsb, maxf, lnflag, 0);

    // ---- layer 2: pow = adj^4, d = 512, K = 608 ----
    k_spmm<<<NN/4, dim3(NH/8, 4), 0, stream>>>(rowcnt, colidx, vals, featsb, t1b, NH, NH, a_sm, -1);
    k_spmm<<<NN/4, dim3(NH/8, 4), 0, stream>>>(rowcnt, colidx, vals, t1b, t2b, NH, NH, a_sm, -1);
    k_spmm<<<NN/4, dim3(NH/8, 4), 0, stream>>>(rowcnt, colidx, vals, t2b, t1b, NH, NH, a_sm, -1);
    k_spmm<<<NN/4, dim3(NH/8, 4), 0, stream>>>(rowcnt, colidx, vals, t1b, mat2, NH, K1, a_sm, 10);
    k_gemm_mfma<<<512, 256, 0, stream>>>(mat2, Wt2, b1_1, tmpo, K1);
    k_l2norm<<<NN, 256, 0, stream>>>(tmpo, featsb, maxf, lnflag, 0);

    // ---- final ----
    k_final<<<NN / 8, 256, 0, stream>>>(features, maxf, W2, b2, out);
}

// Round 4
// 223.260 us; speedup vs baseline: 3.0052x; 1.3873x over previous
//
#include <hip/hip_runtime.h>
#include <hip/hip_bf16.h>
#include <math.h>

typedef unsigned long long u64;
typedef unsigned short ushort_t;
typedef float f32x4 __attribute__((ext_vector_type(4)));
typedef short s16x8 __attribute__((ext_vector_type(8)));

#define NN 4096
#define NF 1024
#define NH 512
#define NC 32
#define LDP 40  // padded LDS row stride (bf16 elems) for MFMA tiles
#define K0 (NF + 3*NC)  // 1120
#define K1 (NH + 3*NC)  // 608

__device__ inline float bf2f(ushort_t u) {
    unsigned int v = ((unsigned int)u) << 16;
    return __uint_as_float(v);
}
__device__ inline ushort_t f2bf(float f) {
    __hip_bfloat16 h = __float2bfloat16(f);
    return *(ushort_t*)&h;
}

// ---------------- fused build: B1 bitset + padded ELL (single adj pass) ----------------
// one wave per row; lane l owns bit-word l (columns 64l..64l+63)
__global__ __launch_bounds__(64) void k_build(const float* __restrict__ adj, u64* __restrict__ B1,
                                              int* __restrict__ rowcnt, int* __restrict__ colidx,
                                              float* __restrict__ vals) {
    int i = blockIdx.x;
    int l = threadIdx.x; // 64
    const float* row = adj + (size_t)i * NN + l * 64;
    const float4* row4 = (const float4*)row;
    u64 w = 0;
    #pragma unroll
    for (int k = 0; k < 16; ++k) {
        float4 v = row4[k];
        if (v.x > 0.f) w |= 1ULL << (4*k + 0);
        if (v.y > 0.f) w |= 1ULL << (4*k + 1);
        if (v.z > 0.f) w |= 1ULL << (4*k + 2);
        if (v.w > 0.f) w |= 1ULL << (4*k + 3);
    }
    B1[(size_t)i*64 + l] = w;
    int cnt = __popcll(w);
    // inclusive wave scan -> exclusive offset (column-sorted, deterministic)
    int pre = cnt;
    #pragma unroll
    for (int o = 1; o < 64; o <<= 1) {
        int u = __shfl_up(pre, o, 64);
        if (l >= o) pre += u;
    }
    int excl = pre - cnt;
    int total = __shfl(pre, 63, 64);
    u64 ww = w;
    int idx = excl;
    while (ww) {
        int b = __ffsll((unsigned long long)ww) - 1;
        ww &= ww - 1;
        if (idx < 64) {
            colidx[i*64 + idx] = l*64 + b;
            vals[i*64 + idx] = row[b];   // L1 hit
        }
        ++idx;
    }
    int tot = total < 64 ? total : 64;
    // zero-fill padding so spmm can run a multiple-of-4 trip count
    for (int s = tot + l; s < 64; s += 64) {
        colidx[i*64 + s] = 0;
        vals[i*64 + s] = 0.f;
    }
    if (l == 0) {
        int r4 = (tot + 3) & ~3;
        rowcnt[i] = r4 < 64 ? r4 : 64;
    }
}

// ---------------- fused prep: featbf | label bitsets | 3x W-transpose | alpha softmax ----------------
__global__ __launch_bounds__(256) void k_prep(const float* __restrict__ features,
                                              __hip_bfloat16* __restrict__ featb,
                                              const float* __restrict__ y, u64* __restrict__ LC,
                                              const float* __restrict__ W0,
                                              const float* __restrict__ W1_0,
                                              const float* __restrict__ W1_1,
                                              __hip_bfloat16* __restrict__ Wt0,
                                              __hip_bfloat16* __restrict__ Wt1,
                                              __hip_bfloat16* __restrict__ Wt2,
                                              const float* __restrict__ alphas,
                                              float* __restrict__ a_sm) {
    __shared__ float tile[32][33];
    int b = blockIdx.x;
    int t = threadIdx.x;
    if (b < 4096) {
        int base = b * 1024 + t * 4;
        float4 v = *(const float4*)&features[base];
        ushort4 o;
        o.x = f2bf(v.x); o.y = f2bf(v.y); o.z = f2bf(v.z); o.w = f2bf(v.w);
        *(ushort4*)&((ushort_t*)featb)[base] = o;
    } else if (b < 4112) {
        int w = (b - 4096) * 4 + (t >> 6);
        int l = t & 63;
        const float* yr = y + (size_t)(w*64 + l) * NC;
        for (int c = 0; c < NC; ++c) {
            u64 m = __ballot(yr[c] > 0.5f);
            if (l == c) LC[c*64 + w] = m;
        }
    } else {
        const float* W; __hip_bfloat16* Wt; int K, ktiles, idx;
        if (b < 4672)      { W = W0;   Wt = Wt0; K = K0; ktiles = 35; idx = b - 4112; }
        else if (b < 4976) { W = W1_0; Wt = Wt1; K = K1; ktiles = 19; idx = b - 4672; }
        else if (b < 5280) { W = W1_1; Wt = Wt2; K = K1; ktiles = 19; idx = b - 4976; }
        else {
            if (t == 0) {
                for (int i = 0; i < 3; ++i) {
                    float m = -1e30f;
                    for (int j = 0; j < 5; ++j) m = fmaxf(m, alphas[i*5+j]);
                    float e[5]; float s = 0.f;
                    for (int j = 0; j < 5; ++j) { e[j] = expf(alphas[i*5+j] - m); s += e[j]; }
                    for (int j = 0; j < 5; ++j) a_sm[i*5+j] = e[j] / s;
                }
            }
            return;
        }
        int kb = (idx % ktiles) * 32, nb = (idx / ktiles) * 32;
        int tc = t & 31, tr8 = t >> 5;
        for (int r = tr8; r < 32; r += 8)
            tile[r][tc] = W[(size_t)(kb + r) * NH + nb + tc];
        __syncthreads();
        ushort_t* Wu = (ushort_t*)Wt;
        for (int r = tr8; r < 32; r += 8)
            Wu[(size_t)(nb + r) * K + kb + tc] = f2bf(tile[tc][r]);
    }
}

// ---------------- boolean matrix product, 4-wave split per row ----------------
__global__ __launch_bounds__(256) void k_bsquare(const u64* __restrict__ Bidx,
                                                 const u64* __restrict__ Bdat,
                                                 u64* __restrict__ Bout) {
    int i = blockIdx.x;
    int t = threadIdx.x;
    int wid = t >> 6, lane = t & 63;
    __shared__ u64 ridx[64];
    __shared__ u64 part[4][64];
    if (t < 64) ridx[t] = Bidx[(size_t)i*64 + t];
    __syncthreads();
    u64 acc = 0;
    for (int u = wid*16; u < wid*16 + 16; ++u) {
        u64 w = ridx[u];
        while (w) {
            int k = u*64 + (__ffsll((unsigned long long)w) - 1);
            w &= (w - 1);
            acc |= Bdat[(size_t)k*64 + lane];
        }
    }
    part[wid][lane] = acc;
    __syncthreads();
    if (t < 64) Bout[(size_t)i*64 + t] = part[0][t] | part[1][t] | part[2][t] | part[3][t];
}

// ---------------- 64x64-tile bit transpose, all three matrices (grid.z) ----------------
__global__ void k_btrans(const u64* __restrict__ B1, const u64* __restrict__ B2,
                         const u64* __restrict__ B4, u64* __restrict__ B1T,
                         u64* __restrict__ B2T, u64* __restrict__ B4T) {
    const u64* B; u64* BT;
    switch (blockIdx.z) {
        case 0: B = B1; BT = B1T; break;
        case 1: B = B2; BT = B2T; break;
        default: B = B4; BT = B4T; break;
    }
    int I = blockIdx.x, J = blockIdx.y;
    int t = threadIdx.x; // 64
    __shared__ u64 ld[64];
    ld[t] = B[(size_t)(I*64 + t)*64 + J];
    __syncthreads();
    u64 out = 0;
    for (int r = 0; r < 64; ++r) out |= ((ld[r] >> t) & 1ULL) << r;
    BT[(size_t)(J*64 + t)*64 + I] = out;
}

// ---------------- y columns: LDS-transposed LC, 8 rows/block, fused out+in ----------------
__global__ __launch_bounds__(256) void k_ymat(const u64* __restrict__ B1, const u64* __restrict__ B1T,
                       const u64* __restrict__ B2, const u64* __restrict__ B2T,
                       const u64* __restrict__ B4, const u64* __restrict__ B4T,
                       const u64* __restrict__ LC, const float* __restrict__ a_sm,
                       __hip_bfloat16* __restrict__ mat0, __hip_bfloat16* __restrict__ mat1,
                       __hip_bfloat16* __restrict__ mat2) {
    int layer = blockIdx.y;
    const u64 *B, *BT; const float* asp; ushort_t* m; int d, K;
    if (layer == 0)      { B = B1; BT = B1T; asp = a_sm;      m = (ushort_t*)mat0; d = NF; K = K0; }
    else if (layer == 1) { B = B2; BT = B2T; asp = a_sm + 5;  m = (ushort_t*)mat1; d = NH; K = K1; }
    else                 { B = B4; BT = B4T; asp = a_sm + 10; m = (ushort_t*)mat2; d = NH; K = K1; }
    __shared__ u64 LCt[64 * 32];        // [w][c] transposed label bitsets
    __shared__ u64 rows[8][64], rowsT[8][64];
    int rb = blockIdx.x * 8;
    int t = threadIdx.x;
    for (int k = t; k < 2048; k += 256) {
        int c = k >> 6, w = k & 63;
        LCt[w*32 + c] = LC[k];
    }
    for (int k = t; k < 512; k += 256) {
        int r = k >> 6, w = k & 63;
        rows[r][w]  = B[(size_t)(rb + r)*64 + w];
        rowsT[r][w] = BT[(size_t)(rb + r)*64 + w];
    }
    __syncthreads();
    int wid = t >> 6, lane = t & 63;
    int h = lane >> 5, c = lane & 31;
    int r = wid * 2 + h;
    int co = 0, ci = 0;
    #pragma unroll
    for (int w = 0; w < 64; ++w) {
        u64 lc = LCt[w*32 + c];
        co += __popcll(rows[r][w]  & lc);
        ci += __popcll(rowsT[r][w] & lc);
    }
    float a1 = asp[1], a2 = asp[2], a3 = asp[3];
    size_t i = rb + r;
    m[i*K + d + c]      = f2bf(a1 * (float)co);
    m[i*K + d + 32 + c] = f2bf(a2 * (float)ci);
    m[i*K + d + 64 + c] = f2bf(a3 * (float)(co + ci));
}

// ---------------- SpMM (padded ELL): one wave per row, 4 gathers in flight ----------------
__global__ void k_spmm(const int* __restrict__ rowcnt, const int* __restrict__ colidx,
                       const float* __restrict__ vals, const __hip_bfloat16* __restrict__ X,
                       __hip_bfloat16* __restrict__ Y, int d, int ystride,
                       const float* __restrict__ a_sm, int ai) {
    int i = blockIdx.x * 4 + threadIdx.y;
    int t = threadIdx.x; // d/8
    int cnt = rowcnt[i];  // multiple of 4
    const ushort_t* Xu = (const ushort_t*)X;
    float acc[8] = {0,0,0,0,0,0,0,0};
    for (int p = 0; p < cnt; p += 4) {
        int4   cc = *(const int4*)&colidx[i*64 + p];
        float4 vv = *(const float4*)&vals[i*64 + p];
        s16x8 x0 = *(const s16x8*)&Xu[(size_t)cc.x * d + 8*t];
        s16x8 x1 = *(const s16x8*)&Xu[(size_t)cc.y * d + 8*t];
        s16x8 x2 = *(const s16x8*)&Xu[(size_t)cc.z * d + 8*t];
        s16x8 x3 = *(const s16x8*)&Xu[(size_t)cc.w * d + 8*t];
        #pragma unroll
        for (int j = 0; j < 8; ++j) {
            acc[j] += vv.x * bf2f((ushort_t)x0[j]);
            acc[j] += vv.y * bf2f((ushort_t)x1[j]);
            acc[j] += vv.z * bf2f((ushort_t)x2[j]);
            acc[j] += vv.w * bf2f((ushort_t)x3[j]);
        }
    }
    float alpha = (ai >= 0) ? a_sm[ai] : 1.0f;
    s16x8 o;
    #pragma unroll
    for (int j = 0; j < 8; ++j) o[j] = (short)f2bf(alpha * acc[j]);
    *(s16x8*)&((ushort_t*)Y)[(size_t)i*ystride + 8*t] = o;
}

// ---------------- MFMA GEMM: C[NN][NH] fp32 = mat[NN][K] bf16 @ Wt[NH][K]^T + b ----------------
__global__ __launch_bounds__(256) void k_gemm_mfma(const __hip_bfloat16* __restrict__ mat,
                                                   const __hip_bfloat16* __restrict__ Wt,
                                                   const float* __restrict__ b,
                                                   float* __restrict__ C, int K) {
    __shared__ ushort_t As[64 * LDP];
    __shared__ ushort_t Bs[64 * LDP];
    int bx = blockIdx.x;                 // 0..511
    int xcd = bx & 7, rest = bx >> 3;
    int nt = rest & 7, mt = (rest >> 3) * 8 + xcd;
    int bm = mt * 64, bn = nt * 64;
    int tid = threadIdx.x;
    int srow = tid >> 2, scol = (tid & 3) * 8;
    int wid = tid >> 6, lane = tid & 63;
    int fr = lane & 15, fk = (lane >> 4) * 8;
    f32x4 acc[4] = {{0,0,0,0},{0,0,0,0},{0,0,0,0},{0,0,0,0}};
    const ushort_t* Au = (const ushort_t*)mat + (size_t)(bm + srow) * K + scol;
    const ushort_t* Bu = (const ushort_t*)Wt  + (size_t)(bn + srow) * K + scol;
    for (int k0 = 0; k0 < K; k0 += 32) {
        *(s16x8*)&As[srow * LDP + scol] = *(const s16x8*)(Au + k0);
        *(s16x8*)&Bs[srow * LDP + scol] = *(const s16x8*)(Bu + k0);
        __syncthreads();
        s16x8 af = *(const s16x8*)&As[(wid * 16 + fr) * LDP + fk];
        #pragma unroll
        for (int j = 0; j < 4; ++j) {
            s16x8 bfv = *(const s16x8*)&Bs[(j * 16 + fr) * LDP + fk];
            acc[j] = __builtin_amdgcn_mfma_f32_16x16x32_bf16(af, bfv, acc[j], 0, 0, 0);
        }
        __syncthreads();
    }
    int drow = bm + wid * 16 + (lane >> 4) * 4;
    #pragma unroll
    for (int j = 0; j < 4; ++j) {
        int col = bn + j * 16 + fr;
        float bias = b[col];
        #pragma unroll
        for (int r = 0; r < 4; ++r)
            C[(size_t)(drow + r) * NH + col] = acc[j][r] + bias;
    }
}

// ---------------- row l2norm; write feats bf16 + running max fp32 (layers 0,1) ----------------
__global__ void k_l2norm(const float* __restrict__ tmp, __hip_bfloat16* __restrict__ featsb,
                         float* __restrict__ maxf, const int* __restrict__ lnflag,
                         int first) {
    int i = blockIdx.x;
    int t = threadIdx.x; // 256
    float v0 = tmp[(size_t)i*NH + t];
    float v1 = tmp[(size_t)i*NH + 256 + t];
    float ss = v0*v0 + v1*v1;
    __shared__ float red[4];
    #pragma unroll
    for (int o = 32; o > 0; o >>= 1) ss += __shfl_down(ss, o, 64);
    if ((t & 63) == 0) red[t >> 6] = ss;
    __syncthreads();
    float tot = red[0] + red[1] + red[2] + red[3];
    float scale = 1.0f;
    if (*lnflag) {
        float n = sqrtf(tot);
        scale = 1.0f / fmaxf(n, 1e-12f);
    }
    v0 *= scale; v1 *= scale;
    ushort_t* fb = (ushort_t*)featsb;
    fb[(size_t)i*NH + t]       = f2bf(v0);
    fb[(size_t)i*NH + 256 + t] = f2bf(v1);
    if (first) {
        maxf[(size_t)i*NH + t] = v0;
        maxf[(size_t)i*NH + 256 + t] = v1;
    } else {
        maxf[(size_t)i*NH + t] = fmaxf(maxf[(size_t)i*NH + t], v0);
        maxf[(size_t)i*NH + 256 + t] = fmaxf(maxf[(size_t)i*NH + 256 + t], v1);
    }
}

// ---------------- fused: layer-2 l2norm + max + relu(concat) @ W2 + b2 -> log_softmax ----------------
__global__ __launch_bounds__(256) void k_l2final(const float* __restrict__ tmpo,
                                                 const float* __restrict__ maxf,
                                                 const float* __restrict__ feat0,
                                                 const float* __restrict__ W2,
                                                 const float* __restrict__ b2,
                                                 const int* __restrict__ lnflag,
                                                 float* __restrict__ out) {
    int rb = blockIdx.x * 8;
    int t = threadIdx.x; // 256
    __shared__ float rows[8][NF + NH];
    __shared__ float part[8][8][32];
    for (int r = 0; r < 8; ++r) {
        const float* f0 = feat0 + (size_t)(rb + r) * NF;
        for (int c = t; c < NF; c += 256) rows[r][c] = fmaxf(f0[c], 0.f);
    }
    int wid = t >> 6, lane = t & 63;
    int ln = *lnflag;
    #pragma unroll
    for (int rr = 0; rr < 2; ++rr) {
        int r = wid * 2 + rr;
        const float4* tp = (const float4*)(tmpo + (size_t)(rb + r) * NH + lane * 8);
        float4 va = tp[0], vb = tp[1];
        float ss = va.x*va.x + va.y*va.y + va.z*va.z + va.w*va.w
                 + vb.x*vb.x + vb.y*vb.y + vb.z*vb.z + vb.w*vb.w;
        #pragma unroll
        for (int o = 32; o > 0; o >>= 1) ss += __shfl_xor(ss, o, 64);
        float scale = ln ? 1.0f / fmaxf(sqrtf(ss), 1e-12f) : 1.0f;
        const float4* mf = (const float4*)(maxf + (size_t)(rb + r) * NH + lane * 8);
        float4 ma = mf[0], mb = mf[1];
        float* dst = &rows[r][NF + lane * 8];
        dst[0] = fmaxf(fmaxf(ma.x, va.x*scale), 0.f);
        dst[1] = fmaxf(fmaxf(ma.y, va.y*scale), 0.f);
        dst[2] = fmaxf(fmaxf(ma.z, va.z*scale), 0.f);
        dst[3] = fmaxf(fmaxf(ma.w, va.w*scale), 0.f);
        dst[4] = fmaxf(fmaxf(mb.x, vb.x*scale), 0.f);
        dst[5] = fmaxf(fmaxf(mb.y, vb.y*scale), 0.f);
        dst[6] = fmaxf(fmaxf(mb.z, vb.z*scale), 0.f);
        dst[7] = fmaxf(fmaxf(mb.w, vb.w*scale), 0.f);
    }
    __syncthreads();
    int c = t & 31, g = t >> 5;
    float acc[8] = {0,0,0,0,0,0,0,0};
    for (int k = g * 192; k < (g + 1) * 192; ++k) {
        float w = W2[(size_t)k * NC + c];
        #pragma unroll
        for (int r = 0; r < 8; ++r) acc[r] += rows[r][k] * w;
    }
    #pragma unroll
    for (int r = 0; r < 8; ++r) part[g][r][c] = acc[r];
    __syncthreads();
    int r = g;
    float lg = b2[c];
    #pragma unroll
    for (int gg = 0; gg < 8; ++gg) lg += part[gg][r][c];
    float m = lg;
    #pragma unroll
    for (int o = 16; o > 0; o >>= 1) m = fmaxf(m, __shfl_xor(m, o, 32));
    float e = expf(lg - m), s = e;
    #pragma unroll
    for (int o = 16; o > 0; o >>= 1) s += __shfl_xor(s, o, 32);
    out[(size_t)(rb + r) * NC + c] = lg - m - logf(s);
}

extern "C" void kernel_launch(void* const* d_in, const int* in_sizes, int n_in,
                              void* d_out, int out_size, void* d_ws, size_t ws_size,
                              hipStream_t stream) {
    const float* adj      = (const float*)d_in[0];
    const float* features = (const float*)d_in[1];
    const float* y        = (const float*)d_in[2];
    const float* W0       = (const float*)d_in[3];
    const float* b0       = (const float*)d_in[4];
    const float* W1_0     = (const float*)d_in[5];
    const float* b1_0     = (const float*)d_in[6];
    const float* W1_1     = (const float*)d_in[7];
    const float* b1_1     = (const float*)d_in[8];
    const float* W2       = (const float*)d_in[9];
    const float* b2       = (const float*)d_in[10];
    const float* alphas   = (const float*)d_in[11];
    const int*   lnflag   = (const int*)d_in[12];
    float* out = (float*)d_out;

    char* ws = (char*)d_ws;
    size_t off = 0;
    auto alloc = [&](size_t bytes) -> char* {
        char* p = ws + off;
        off = (off + bytes + 255) & ~(size_t)255;
        return p;
    };
    float* a_sm   = (float*)alloc(16 * 4);
    int*   rowcnt = (int*)alloc((size_t)NN * 4);
    int*   colidx = (int*)alloc((size_t)NN * 64 * 4);
    float* vals   = (float*)alloc((size_t)NN * 64 * 4);
    u64* B1  = (u64*)alloc((size_t)NN * 64 * 8);
    u64* B2  = (u64*)alloc((size_t)NN * 64 * 8);
    u64* B4  = (u64*)alloc((size_t)NN * 64 * 8);
    u64* B1T = (u64*)alloc((size_t)NN * 64 * 8);
    u64* B2T = (u64*)alloc((size_t)NN * 64 * 8);
    u64* B4T = (u64*)alloc((size_t)NN * 64 * 8);
    u64* LC  = (u64*)alloc((size_t)NC * 64 * 8);
    __hip_bfloat16* featb  = (__hip_bfloat16*)alloc((size_t)NN * NF * 2);
    __hip_bfloat16* featsb = (__hip_bfloat16*)alloc((size_t)NN * NH * 2);
    __hip_bfloat16* t1b    = (__hip_bfloat16*)alloc((size_t)NN * NH * 2);
    __hip_bfloat16* mat0   = (__hip_bfloat16*)alloc((size_t)NN * K0 * 2);
    __hip_bfloat16* mat1   = (__hip_bfloat16*)alloc((size_t)NN * K1 * 2);
    __hip_bfloat16* mat2   = (__hip_bfloat16*)alloc((size_t)NN * K1 * 2);
    __hip_bfloat16* Wt0    = (__hip_bfloat16*)alloc((size_t)NH * K0 * 2);
    __hip_bfloat16* Wt1    = (__hip_bfloat16*)alloc((size_t)NH * K1 * 2);
    __hip_bfloat16* Wt2    = (__hip_bfloat16*)alloc((size_t)NH * K1 * 2);
    float* tmpo = (float*)alloc((size_t)NN * NH * 4);
    float* maxf = (float*)alloc((size_t)NN * NH * 4);
    __hip_bfloat16* t2b = (__hip_bfloat16*)tmpo; // alias: dead before gemm writes tmpo

    // ---- setup ----
    k_build<<<NN, 64, 0, stream>>>(adj, B1, rowcnt, colidx, vals);
    k_prep<<<5281, 256, 0, stream>>>(features, featb, y, LC, W0, W1_0, W1_1,
                                     Wt0, Wt1, Wt2, alphas, a_sm);
    k_bsquare<<<NN, 256, 0, stream>>>(B1, B1, B2);
    k_bsquare<<<NN, 256, 0, stream>>>(B2, B2, B4);
    k_btrans<<<dim3(64, 64, 3), 64, 0, stream>>>(B1, B2, B4, B1T, B2T, B4T);
    k_ymat<<<dim3(NN/8, 3), 256, 0, stream>>>(B1, B1T, B2, B2T, B4, B4T, LC, a_sm,
                                              mat0, mat1, mat2);

    // ---- layer 0: pow = adj, d = 1024, K = 1120 ----
    k_spmm<<<NN/4, dim3(NF/8, 4), 0, stream>>>(rowcnt, colidx, vals, featb, mat0, NF, K0, a_sm, 0);
    k_gemm_mfma<<<512, 256, 0, stream>>>(mat0, Wt0, b0, tmpo, K0);
    k_l2norm<<<NN, 256, 0, stream>>>(tmpo, featsb, maxf, lnflag, 1);

    // ---- layer 1: pow = adj^2, d = 512, K = 608 ----
    k_spmm<<<NN/4, dim3(NH/8, 4), 0, stream>>>(rowcnt, colidx, vals, featsb, t1b, NH, NH, a_sm, -1);
    k_spmm<<<NN/4, dim3(NH/8, 4), 0, stream>>>(rowcnt, colidx, vals, t1b, mat1, NH, K1, a_sm, 5);
    k_gemm_mfma<<<512, 256, 0, stream>>>(mat1, Wt1, b1_0, tmpo, K1);
    k_l2norm<<<NN, 256, 0, stream>>>(tmpo, featsb, maxf, lnflag, 0);

    // ---- layer 2: pow = adj^4, d = 512, K = 608 ----
    k_spmm<<<NN/4, dim3(NH/8, 4), 0, stream>>>(rowcnt, colidx, vals, featsb, t1b, NH, NH, a_sm, -1);
    k_spmm<<<NN/4, dim3(NH/8, 4), 0, stream>>>(rowcnt, colidx, vals, t1b, t2b, NH, NH, a_sm, -1);
    k_spmm<<<NN/4, dim3(NH/8, 4), 0, stream>>>(rowcnt, colidx, vals, t2b, t1b, NH, NH, a_sm, -1);
    k_spmm<<<NN/4, dim3(NH/8, 4), 0, stream>>>(rowcnt, colidx, vals, t1b, mat2, NH, K1, a_sm, 10);
    k_gemm_mfma<<<512, 256, 0, stream>>>(mat2, Wt2, b1_1, tmpo, K1);

    // ---- fused layer-2 l2norm + final ----
    k_l2final<<<NN/8, 256, 0, stream>>>(tmpo, maxf, features, W2, b2, lnflag, out);
}